// Round 3
// baseline (476.482 us; speedup 1.0000x reference)
//
#include <hip/hip_runtime.h>
#include <math.h>

// GNO layer, algebraic refactor:
//   G[j]    = feat[j] @ W1[3:67] + b1                    (phase 1)
//   out[i]  = feat[i] @ Ws + bs + b2                     (phase 1, skip pre-write)
//   hbar_i  = (1/K) sum_k GELU( (coords[j]-coords[i]) @ W1[0:3] + G[j] )
//   out[i] += hbar_i @ W2                                (phase 2)
//
// Broadcasts use v_readlane (SGPR operand into v_fma) instead of LDS:
// lane c owns channel c; readlane(x, d) gives x[d] wave-uniform.

#define KNN 16

__device__ __forceinline__ float lane_bcast(float v, int lane) {
    return __int_as_float(__builtin_amdgcn_readlane(__float_as_int(v), lane));
}

// Phase 1: one wave per point. Weight columns live in VGPRs (no LDS).
__global__ __launch_bounds__(256, 3) void gno_phase1(
    const float* __restrict__ features, const float* __restrict__ W1,
    const float* __restrict__ b1, const float* __restrict__ Ws,
    const float* __restrict__ bs, const float* __restrict__ b2,
    float* __restrict__ G, float* __restrict__ outskip, int n)
{
    const int c = threadIdx.x;  // channel 0..63 == lane
    float w1r[64], wsr[64];
    #pragma unroll
    for (int d = 0; d < 64; ++d) {
        w1r[d] = W1[(3 + d) * 64 + c];   // rows 3..66 of W1
        wsr[d] = Ws[d * 64 + c];
    }
    const float b1c = b1[c];
    const float sbc = bs[c] + b2[c];

    const int wave   = blockIdx.x * 4 + threadIdx.y;
    const int stride = gridDim.x * 4;
    int i = wave;
    float f = (i < n) ? features[(size_t)i * 64 + c] : 0.0f;
    for (; i < n; i += stride) {
        const float fcur = f;
        const int inext = i + stride;
        if (inext < n) f = features[(size_t)inext * 64 + c];  // prefetch next row
        float a1 = b1c, a2 = sbc;
        #pragma unroll
        for (int d = 0; d < 64; ++d) {
            const float fd = lane_bcast(fcur, d);
            a1 = fmaf(fd, w1r[d], a1);
            a2 = fmaf(fd, wsr[d], a2);
        }
        G[(size_t)i * 64 + c]       = a1;
        outskip[(size_t)i * 64 + c] = a2;
    }
}

// Phase 2: one wave per point; only W2 in LDS (16.4 KB -> 8 blocks/CU).
__global__ __launch_bounds__(256, 8) void gno_phase2(
    const float* __restrict__ coords, const int* __restrict__ idx,
    const float* __restrict__ W1, const float* __restrict__ W2,
    const float* __restrict__ G, float* __restrict__ out, int n)
{
    __shared__ float w2s[64 * 64];
    const int tid = threadIdx.y * 64 + threadIdx.x;
    #pragma unroll
    for (int t = 0; t < 16; ++t) w2s[t * 256 + tid] = W2[t * 256 + tid];
    const int c = threadIdx.x;
    const float w1px = W1[c], w1py = W1[64 + c], w1pz = W1[128 + c];
    __syncthreads();

    const int wave   = blockIdx.x * 4 + threadIdx.y;
    const int stride = gridDim.x * 4;
    for (int i = wave; i < n; i += stride) {
        // idx row coalesced into lanes 0..15, then scalarized per neighbor
        const int vj = idx[i * KNN + (c & 15)];
        const float cix = coords[(size_t)i * 3 + 0];
        const float ciy = coords[(size_t)i * 3 + 1];
        const float ciz = coords[(size_t)i * 3 + 2];
        // fold -coords[i] @ w1p into one per-point base term
        float base = cix * w1px;
        base = fmaf(ciy, w1py, base);
        base = fmaf(ciz, w1pz, base);

        float acc = 0.0f;
        #pragma unroll
        for (int k = 0; k < KNN; ++k) {
            const int sj = __builtin_amdgcn_readlane(vj, k);   // uniform neighbor id
            const float* cj = coords + (size_t)sj * 3;         // uniform -> s_load
            float pre = G[((size_t)sj << 6) + c] - base;       // coalesced 256B gather
            pre = fmaf(cj[0], w1px, pre);
            pre = fmaf(cj[1], w1py, pre);
            pre = fmaf(cj[2], w1pz, pre);
            // exact GELU (erf form)
            acc += 0.5f * pre * (1.0f + erff(pre * 0.70710678118654752f));
        }
        acc *= (1.0f / KNN);

        float o = out[(size_t)i * 64 + c];   // skip written by phase1
        #pragma unroll
        for (int d = 0; d < 64; ++d) {
            const float hd = lane_bcast(acc, d);
            o = fmaf(hd, w2s[d * 64 + c], o);
        }
        out[(size_t)i * 64 + c] = o;
    }
}

extern "C" void kernel_launch(void* const* d_in, const int* in_sizes, int n_in,
                              void* d_out, int out_size, void* d_ws, size_t ws_size,
                              hipStream_t stream) {
    const float* coords   = (const float*)d_in[0];
    const float* features = (const float*)d_in[1];
    const int*   idx      = (const int*)d_in[2];
    const float* W1       = (const float*)d_in[3];
    const float* b1       = (const float*)d_in[4];
    const float* W2       = (const float*)d_in[5];
    const float* b2       = (const float*)d_in[6];
    const float* Ws       = (const float*)d_in[7];
    const float* bs       = (const float*)d_in[8];
    float* out = (float*)d_out;
    const int n = in_sizes[0] / 3;          // 100000
    float* G = (float*)d_ws;                // n*64 floats = 25.6 MB

    dim3 block(64, 4);
    gno_phase1<<<dim3(768),  block, 0, stream>>>(features, W1, b1, Ws, bs, b2, G, out, n);
    gno_phase2<<<dim3(2048), block, 0, stream>>>(coords, idx, W1, W2, G, out, n);
}

// Round 4
// 448.531 us; speedup vs baseline: 1.0623x; 1.0623x over previous
//
#include <hip/hip_runtime.h>
#include <hip/hip_fp16.h>
#include <math.h>

// GNO layer, algebraic refactor v3:
//   Gp[j,c] = feat[j] @ W1[3:67,c] + b1[c] + coords[j] @ W1[0:3,c]   (fp16, phase1a)
//   out[i]  = feat[i] @ Ws + bs + b2                                  (phase1b)
//   P[i,c]  = coords[i] @ W1[0:3,c]        (3 FMAs, recomputed in phase2)
//   hbar_i  = (1/K) sum_k GELU( Gp[idx[i,k]] - P[i] )
//   out[i] += hbar_i @ W2                                             (phase2)
//
// The coords fold removes the per-neighbor coords gather; fp16 Gp halves the
// random-gather bytes (128 B/row). Broadcasts via v_readlane (SGPR into v_fma).

#define KNN 16

__device__ __forceinline__ float lane_bcast(float v, int lane) {
    return __int_as_float(__builtin_amdgcn_readlane(__float_as_int(v), lane));
}

// Phase 1a: Gp = feat @ W1[3:] + b1 + coords @ W1[:3], stored fp16.
// 64+3 weight VGPRs -> ~5 waves/SIMD; 2 points per iter for ILP.
__global__ __launch_bounds__(256) void gno_phase1a(
    const float* __restrict__ features, const float* __restrict__ coords,
    const float* __restrict__ W1, const float* __restrict__ b1,
    __half* __restrict__ Gp, int n)
{
    const int c = threadIdx.x;
    float w1r[64];
    #pragma unroll
    for (int d = 0; d < 64; ++d) w1r[d] = W1[(3 + d) * 64 + c];
    const float w1px = W1[c], w1py = W1[64 + c], w1pz = W1[128 + c];
    const float b1c = b1[c];

    const int wave   = blockIdx.x * 4 + threadIdx.y;
    const int stride = gridDim.x * 4;
    for (int i0 = wave * 2; i0 < n; i0 += stride * 2) {
        const int i1 = i0 + 1;
        const bool has1 = (i1 < n);
        const float f0 = features[(size_t)i0 * 64 + c];
        const float f1 = has1 ? features[(size_t)i1 * 64 + c] : 0.0f;
        float a0 = fmaf(coords[(size_t)i0 * 3 + 0], w1px, b1c);
        a0 = fmaf(coords[(size_t)i0 * 3 + 1], w1py, a0);
        a0 = fmaf(coords[(size_t)i0 * 3 + 2], w1pz, a0);
        float a1 = b1c;
        if (has1) {
            a1 = fmaf(coords[(size_t)i1 * 3 + 0], w1px, a1);
            a1 = fmaf(coords[(size_t)i1 * 3 + 1], w1py, a1);
            a1 = fmaf(coords[(size_t)i1 * 3 + 2], w1pz, a1);
        }
        #pragma unroll
        for (int d = 0; d < 64; ++d) {
            a0 = fmaf(lane_bcast(f0, d), w1r[d], a0);
            a1 = fmaf(lane_bcast(f1, d), w1r[d], a1);
        }
        Gp[(size_t)i0 * 64 + c] = __float2half(a0);
        if (has1) Gp[(size_t)i1 * 64 + c] = __float2half(a1);
    }
}

// Phase 1b: out = feat @ Ws + bs + b2 (skip pre-write).
__global__ __launch_bounds__(256) void gno_phase1b(
    const float* __restrict__ features, const float* __restrict__ Ws,
    const float* __restrict__ bs, const float* __restrict__ b2,
    float* __restrict__ out, int n)
{
    const int c = threadIdx.x;
    float wsr[64];
    #pragma unroll
    for (int d = 0; d < 64; ++d) wsr[d] = Ws[d * 64 + c];
    const float sbc = bs[c] + b2[c];

    const int wave   = blockIdx.x * 4 + threadIdx.y;
    const int stride = gridDim.x * 4;
    for (int i0 = wave * 2; i0 < n; i0 += stride * 2) {
        const int i1 = i0 + 1;
        const bool has1 = (i1 < n);
        const float f0 = features[(size_t)i0 * 64 + c];
        const float f1 = has1 ? features[(size_t)i1 * 64 + c] : 0.0f;
        float a0 = sbc, a1 = sbc;
        #pragma unroll
        for (int d = 0; d < 64; ++d) {
            a0 = fmaf(lane_bcast(f0, d), wsr[d], a0);
            a1 = fmaf(lane_bcast(f1, d), wsr[d], a1);
        }
        out[(size_t)i0 * 64 + c] = a0;
        if (has1) out[(size_t)i1 * 64 + c] = a1;
    }
}

// Phase 2: gather fp16 Gp rows (128 B), GELU, mean, @W2, += skip.
__global__ __launch_bounds__(256, 8) void gno_phase2(
    const float* __restrict__ coords, const int* __restrict__ idx,
    const float* __restrict__ W1, const float* __restrict__ W2,
    const __half* __restrict__ Gp, float* __restrict__ out, int n)
{
    __shared__ float w2s[64 * 64];
    const int tid = threadIdx.y * 64 + threadIdx.x;
    #pragma unroll
    for (int t = 0; t < 16; ++t) w2s[t * 256 + tid] = W2[t * 256 + tid];
    const int c = threadIdx.x;
    const float w1px = W1[c], w1py = W1[64 + c], w1pz = W1[128 + c];
    __syncthreads();

    const int wave   = blockIdx.x * 4 + threadIdx.y;
    const int stride = gridDim.x * 4;
    for (int i = wave; i < n; i += stride) {
        const int vj = idx[i * KNN + (c & 15)];   // lanes 0..15 carry the row
        float Pi = coords[(size_t)i * 3 + 0] * w1px;
        Pi = fmaf(coords[(size_t)i * 3 + 1], w1py, Pi);
        Pi = fmaf(coords[(size_t)i * 3 + 2], w1pz, Pi);

        float acc = 0.0f;
        #pragma unroll
        for (int k = 0; k < KNN; ++k) {
            const int sj = __builtin_amdgcn_readlane(vj, k);   // uniform neighbor id
            const float pre = __half2float(Gp[((size_t)sj << 6) + c]) - Pi;
            acc += 0.5f * pre * (1.0f + erff(pre * 0.70710678118654752f));
        }
        acc *= (1.0f / KNN);

        float o = out[(size_t)i * 64 + c];       // skip written by phase1b
        #pragma unroll
        for (int d = 0; d < 64; ++d)
            o = fmaf(lane_bcast(acc, d), w2s[d * 64 + c], o);
        out[(size_t)i * 64 + c] = o;
    }
}

extern "C" void kernel_launch(void* const* d_in, const int* in_sizes, int n_in,
                              void* d_out, int out_size, void* d_ws, size_t ws_size,
                              hipStream_t stream) {
    const float* coords   = (const float*)d_in[0];
    const float* features = (const float*)d_in[1];
    const int*   idx      = (const int*)d_in[2];
    const float* W1       = (const float*)d_in[3];
    const float* b1       = (const float*)d_in[4];
    const float* W2       = (const float*)d_in[5];
    const float* b2       = (const float*)d_in[6];
    const float* Ws       = (const float*)d_in[7];
    const float* bs       = (const float*)d_in[8];
    float* out = (float*)d_out;
    const int n = in_sizes[0] / 3;            // 100000
    __half* Gp = (__half*)d_ws;               // n*64 halfs = 12.8 MB

    dim3 block(64, 4);
    gno_phase1a<<<dim3(1024), block, 0, stream>>>(features, coords, W1, b1, Gp, n);
    gno_phase1b<<<dim3(1024), block, 0, stream>>>(features, Ws, bs, b2, out, n);
    gno_phase2 <<<dim3(2048), block, 0, stream>>>(coords, idx, W1, W2, Gp, out, n);
}

// Round 5
// 311.109 us; speedup vs baseline: 1.5316x; 1.4417x over previous
//
#include <hip/hip_runtime.h>
#include <hip/hip_fp16.h>
#include <math.h>

// GNO layer, v4:
//   Gp[j,c] = feat[j] @ W1[3:67,c] + b1[c] + coords[j] @ W1[0:3,c]   (fp16, phase1a)
//   out[i]  = feat[i] @ Ws + bs + b2                                  (phase1b)
//   hbar_i  = (1/K) sum_k GELU( Gp[idx[i,k]] - coords[i] @ W1[0:3] )
//   out[i] += hbar_i @ W2                                             (phase2)
//
// Phase2 v4: packed half2 gathers (one wave-load = 2 neighbor rows, 8 loads
// in flight per point), exp2-based tanh-GELU, lane owns channel pair.

#define KNN 16

__device__ __forceinline__ float lane_bcast(float v, int lane) {
    return __int_as_float(__builtin_amdgcn_readlane(__float_as_int(v), lane));
}

// gelu(x) ~= x * sigmoid(1.5957691*(x + 0.044715 x^3)); exp2-folded constants.
// max |delta| vs exact erf-GELU ~3e-4.
__device__ __forceinline__ float gelu_fast(float x) {
    const float t = x * fmaf(x * x, -0.10294324f, -2.30220821f); // -z*log2(e)
    return x * __builtin_amdgcn_rcpf(1.0f + exp2f(t));
}

// Phase 1a: Gp = feat @ W1[3:] + b1 + coords @ W1[:3], stored fp16. (unchanged)
__global__ __launch_bounds__(256) void gno_phase1a(
    const float* __restrict__ features, const float* __restrict__ coords,
    const float* __restrict__ W1, const float* __restrict__ b1,
    __half* __restrict__ Gp, int n)
{
    const int c = threadIdx.x;
    float w1r[64];
    #pragma unroll
    for (int d = 0; d < 64; ++d) w1r[d] = W1[(3 + d) * 64 + c];
    const float w1px = W1[c], w1py = W1[64 + c], w1pz = W1[128 + c];
    const float b1c = b1[c];

    const int wave   = blockIdx.x * 4 + threadIdx.y;
    const int stride = gridDim.x * 4;
    for (int i0 = wave * 2; i0 < n; i0 += stride * 2) {
        const int i1 = i0 + 1;
        const bool has1 = (i1 < n);
        const float f0 = features[(size_t)i0 * 64 + c];
        const float f1 = has1 ? features[(size_t)i1 * 64 + c] : 0.0f;
        float a0 = fmaf(coords[(size_t)i0 * 3 + 0], w1px, b1c);
        a0 = fmaf(coords[(size_t)i0 * 3 + 1], w1py, a0);
        a0 = fmaf(coords[(size_t)i0 * 3 + 2], w1pz, a0);
        float a1 = b1c;
        if (has1) {
            a1 = fmaf(coords[(size_t)i1 * 3 + 0], w1px, a1);
            a1 = fmaf(coords[(size_t)i1 * 3 + 1], w1py, a1);
            a1 = fmaf(coords[(size_t)i1 * 3 + 2], w1pz, a1);
        }
        #pragma unroll
        for (int d = 0; d < 64; ++d) {
            a0 = fmaf(lane_bcast(f0, d), w1r[d], a0);
            a1 = fmaf(lane_bcast(f1, d), w1r[d], a1);
        }
        Gp[(size_t)i0 * 64 + c] = __float2half(a0);
        if (has1) Gp[(size_t)i1 * 64 + c] = __float2half(a1);
    }
}

// Phase 1b: out = feat @ Ws + bs + b2 (skip pre-write). (unchanged)
__global__ __launch_bounds__(256) void gno_phase1b(
    const float* __restrict__ features, const float* __restrict__ Ws,
    const float* __restrict__ bs, const float* __restrict__ b2,
    float* __restrict__ out, int n)
{
    const int c = threadIdx.x;
    float wsr[64];
    #pragma unroll
    for (int d = 0; d < 64; ++d) wsr[d] = Ws[d * 64 + c];
    const float sbc = bs[c] + b2[c];

    const int wave   = blockIdx.x * 4 + threadIdx.y;
    const int stride = gridDim.x * 4;
    for (int i0 = wave * 2; i0 < n; i0 += stride * 2) {
        const int i1 = i0 + 1;
        const bool has1 = (i1 < n);
        const float f0 = features[(size_t)i0 * 64 + c];
        const float f1 = has1 ? features[(size_t)i1 * 64 + c] : 0.0f;
        float a0 = sbc, a1 = sbc;
        #pragma unroll
        for (int d = 0; d < 64; ++d) {
            a0 = fmaf(lane_bcast(f0, d), wsr[d], a0);
            a1 = fmaf(lane_bcast(f1, d), wsr[d], a1);
        }
        out[(size_t)i0 * 64 + c] = a0;
        if (has1) out[(size_t)i1 * 64 + c] = a1;
    }
}

// Phase 2 v4: packed gathers + fast GELU + readlane epilogue.
__global__ __launch_bounds__(256, 8) void gno_phase2(
    const float* __restrict__ coords, const int* __restrict__ idx,
    const float* __restrict__ W1, const float* __restrict__ W2,
    const __half2* __restrict__ Gp2, float* __restrict__ out, int n)
{
    __shared__ float w2s[64 * 64];
    const int tid = threadIdx.y * 64 + threadIdx.x;
    #pragma unroll
    for (int t = 0; t < 16; ++t) w2s[t * 256 + tid] = W2[t * 256 + tid];

    const int c   = threadIdx.x;          // lane / output channel
    const int m   = c & 31;               // channel-pair id this lane gathers
    const int odd = (c >> 5);             // 0: even-k neighbors, 1: odd-k
    // W1[0:3] columns for channels 2m, 2m+1
    const float wx0 = W1[2 * m],       wx1 = W1[2 * m + 1];
    const float wy0 = W1[64 + 2 * m],  wy1 = W1[64 + 2 * m + 1];
    const float wz0 = W1[128 + 2 * m], wz1 = W1[128 + 2 * m + 1];
    __syncthreads();

    const int wave   = blockIdx.x * 4 + threadIdx.y;
    const int stride = gridDim.x * 4;
    for (int i = wave; i < n; i += stride) {
        const int vj = idx[i * KNN + (c & 15)];   // lanes 0..15 carry the row
        const float cix = coords[(size_t)i * 3 + 0];
        const float ciy = coords[(size_t)i * 3 + 1];
        const float ciz = coords[(size_t)i * 3 + 2];
        float Pi0 = cix * wx0; Pi0 = fmaf(ciy, wy0, Pi0); Pi0 = fmaf(ciz, wz0, Pi0);
        float Pi1 = cix * wx1; Pi1 = fmaf(ciy, wy1, Pi1); Pi1 = fmaf(ciz, wz1, Pi1);

        // ---- issue all 8 packed gathers (each covers 2 neighbor rows) ----
        __half2 gv[8];
        #pragma unroll
        for (int p = 0; p < 8; ++p) {
            const int se = __builtin_amdgcn_readlane(vj, 2 * p);
            const int so = __builtin_amdgcn_readlane(vj, 2 * p + 1);
            const int row = odd ? so : se;        // lanes<32: even k, >=32: odd k
            gv[p] = Gp2[row * 32 + m];            // 4 B/lane, 128 B/row
        }
        // ---- GELU-accumulate channel pair over this half's 8 neighbors ----
        float acc0 = 0.0f, acc1 = 0.0f;
        #pragma unroll
        for (int p = 0; p < 8; ++p) {
            const float2 xy = __half22float2(gv[p]);
            acc0 += gelu_fast(xy.x - Pi0);
            acc1 += gelu_fast(xy.y - Pi1);
        }
        acc0 *= (1.0f / KNN);
        acc1 *= (1.0f / KNN);
        // combine even/odd halves: every lane ends with the full 16-neighbor sum
        acc0 += __shfl_xor(acc0, 32, 64);
        acc1 += __shfl_xor(acc1, 32, 64);

        // ---- epilogue: out[i,c] += sum_d hbar[d] * W2[d,c] ----
        float o = out[(size_t)i * 64 + c];        // skip written by phase1b
        #pragma unroll
        for (int d = 0; d < 64; ++d) {
            const float hd = lane_bcast((d & 1) ? acc1 : acc0, d >> 1);
            o = fmaf(hd, w2s[d * 64 + c], o);
        }
        out[(size_t)i * 64 + c] = o;
    }
}

extern "C" void kernel_launch(void* const* d_in, const int* in_sizes, int n_in,
                              void* d_out, int out_size, void* d_ws, size_t ws_size,
                              hipStream_t stream) {
    const float* coords   = (const float*)d_in[0];
    const float* features = (const float*)d_in[1];
    const int*   idx      = (const int*)d_in[2];
    const float* W1       = (const float*)d_in[3];
    const float* b1       = (const float*)d_in[4];
    const float* W2       = (const float*)d_in[5];
    const float* b2       = (const float*)d_in[6];
    const float* Ws       = (const float*)d_in[7];
    const float* bs       = (const float*)d_in[8];
    float* out = (float*)d_out;
    const int n = in_sizes[0] / 3;            // 100000
    __half* Gp = (__half*)d_ws;               // n*64 halfs = 12.8 MB

    dim3 block(64, 4);
    gno_phase1a<<<dim3(1024), block, 0, stream>>>(features, coords, W1, b1, Gp, n);
    gno_phase1b<<<dim3(1024), block, 0, stream>>>(features, Ws, bs, b2, out, n);
    gno_phase2 <<<dim3(2048), block, 0, stream>>>(coords, idx, W1, W2,
                                                  (const __half2*)Gp, out, n);
}

// Round 6
// 287.113 us; speedup vs baseline: 1.6596x; 1.0836x over previous
//
#include <hip/hip_runtime.h>
#include <hip/hip_fp16.h>
#include <math.h>

// GNO layer, v5:
//   Gp[j,c] = feat[j] @ W1[3:67,c] + b1[c] + coords[j] @ W1[0:3,c]   (fp16)
//   out[i]  = feat[i] @ Ws + bs + b2                                  (skip)
//   hbar_i  = (1/K) sum_k GELU( Gp[idx[i,k]] - coords[i] @ W1[0:3] )
//   out[i] += hbar_i @ W2
//
// v5 changes: phase1a+1b fused (one features pass, shared f-broadcasts);
// phase2 processes 2 points/iter -> 16 gathers in flight, launch_bounds(256,6).

#define KNN 16

__device__ __forceinline__ float lane_bcast(float v, int lane) {
    return __int_as_float(__builtin_amdgcn_readlane(__float_as_int(v), lane));
}

// gelu(x) ~= x * sigmoid(1.5957691*(x + 0.044715 x^3)); exp2-folded constants.
// max |delta| vs exact erf-GELU ~3e-4.
__device__ __forceinline__ float gelu_fast(float x) {
    const float t = x * fmaf(x * x, -0.10294324f, -2.30220821f); // -z*log2(e)
    return x * __builtin_amdgcn_rcpf(1.0f + exp2f(t));
}

// Fused phase 1: Gp (fp16, coords folded) + skip pre-write into out.
// One feature load + one readlane broadcast feeds BOTH weight chains.
__global__ __launch_bounds__(256) void gno_phase1(
    const float* __restrict__ features, const float* __restrict__ coords,
    const float* __restrict__ W1, const float* __restrict__ b1,
    const float* __restrict__ Ws, const float* __restrict__ bs,
    const float* __restrict__ b2, __half* __restrict__ Gp,
    float* __restrict__ out, int n)
{
    const int c = threadIdx.x;
    float w1r[64], wsr[64];
    #pragma unroll
    for (int d = 0; d < 64; ++d) {
        w1r[d] = W1[(3 + d) * 64 + c];
        wsr[d] = Ws[d * 64 + c];
    }
    const float w1px = W1[c], w1py = W1[64 + c], w1pz = W1[128 + c];
    const float b1c = b1[c];
    const float sbc = bs[c] + b2[c];

    const int wave   = blockIdx.x * 4 + threadIdx.y;
    const int stride = gridDim.x * 4;
    for (int i0 = wave * 2; i0 < n; i0 += stride * 2) {
        const int i1 = i0 + 1;
        const bool has1 = (i1 < n);
        const float f0 = features[(size_t)i0 * 64 + c];
        const float f1 = has1 ? features[(size_t)i1 * 64 + c] : 0.0f;

        float a0 = fmaf(coords[(size_t)i0 * 3 + 0], w1px, b1c);
        a0 = fmaf(coords[(size_t)i0 * 3 + 1], w1py, a0);
        a0 = fmaf(coords[(size_t)i0 * 3 + 2], w1pz, a0);
        float a1 = b1c;
        if (has1) {
            a1 = fmaf(coords[(size_t)i1 * 3 + 0], w1px, a1);
            a1 = fmaf(coords[(size_t)i1 * 3 + 1], w1py, a1);
            a1 = fmaf(coords[(size_t)i1 * 3 + 2], w1pz, a1);
        }
        float s0 = sbc, s1 = sbc;
        #pragma unroll
        for (int d = 0; d < 64; ++d) {
            const float fd0 = lane_bcast(f0, d);
            const float fd1 = lane_bcast(f1, d);
            a0 = fmaf(fd0, w1r[d], a0);
            s0 = fmaf(fd0, wsr[d], s0);
            a1 = fmaf(fd1, w1r[d], a1);
            s1 = fmaf(fd1, wsr[d], s1);
        }
        Gp[(size_t)i0 * 64 + c]  = __float2half(a0);
        out[(size_t)i0 * 64 + c] = s0;
        if (has1) {
            Gp[(size_t)i1 * 64 + c]  = __float2half(a1);
            out[(size_t)i1 * 64 + c] = s1;
        }
    }
}

// Phase 2 v5: 2 points/iter, 16 packed gathers in flight, fast GELU,
// readlane epilogue. Lane owns channel pair (2m, 2m+1).
__global__ __launch_bounds__(256, 6) void gno_phase2(
    const float* __restrict__ coords, const int* __restrict__ idx,
    const float* __restrict__ W1, const float* __restrict__ W2,
    const __half2* __restrict__ Gp2, float* __restrict__ out, int n)
{
    __shared__ float w2s[64 * 64];
    const int tid = threadIdx.y * 64 + threadIdx.x;
    #pragma unroll
    for (int t = 0; t < 16; ++t) w2s[t * 256 + tid] = W2[t * 256 + tid];

    const int c   = threadIdx.x;
    const int m   = c & 31;               // channel-pair id this lane gathers
    const int odd = (c >> 5);             // 0: even-k neighbors, 1: odd-k
    const float wx0 = W1[2 * m],       wx1 = W1[2 * m + 1];
    const float wy0 = W1[64 + 2 * m],  wy1 = W1[64 + 2 * m + 1];
    const float wz0 = W1[128 + 2 * m], wz1 = W1[128 + 2 * m + 1];
    __syncthreads();

    const int wave   = blockIdx.x * 4 + threadIdx.y;
    const int stride = gridDim.x * 4;
    for (int i0 = wave * 2; i0 < n; i0 += stride * 2) {
        const int i1 = i0 + 1;
        const bool has1 = (i1 < n);
        // one 32-lane dword load covers BOTH points' idx rows (contiguous)
        const int vj = idx[i0 * KNN + (c & 31)];

        const float c0x = coords[(size_t)i0 * 3 + 0];
        const float c0y = coords[(size_t)i0 * 3 + 1];
        const float c0z = coords[(size_t)i0 * 3 + 2];
        float P00 = c0x * wx0; P00 = fmaf(c0y, wy0, P00); P00 = fmaf(c0z, wz0, P00);
        float P01 = c0x * wx1; P01 = fmaf(c0y, wy1, P01); P01 = fmaf(c0z, wz1, P01);
        float P10 = 0.f, P11 = 0.f;
        if (has1) {
            const float c1x = coords[(size_t)i1 * 3 + 0];
            const float c1y = coords[(size_t)i1 * 3 + 1];
            const float c1z = coords[(size_t)i1 * 3 + 2];
            P10 = c1x * wx0; P10 = fmaf(c1y, wy0, P10); P10 = fmaf(c1z, wz0, P10);
            P11 = c1x * wx1; P11 = fmaf(c1y, wy1, P11); P11 = fmaf(c1z, wz1, P11);
        }

        // ---- issue all 16 packed gathers (8 per point) back-to-back ----
        __half2 gv[16];
        #pragma unroll
        for (int p = 0; p < 8; ++p) {
            const int se = __builtin_amdgcn_readlane(vj, 2 * p);
            const int so = __builtin_amdgcn_readlane(vj, 2 * p + 1);
            const int row = odd ? so : se;
            gv[p] = Gp2[(size_t)row * 32 + m];
        }
        if (has1) {
            #pragma unroll
            for (int p = 0; p < 8; ++p) {
                const int se = __builtin_amdgcn_readlane(vj, 16 + 2 * p);
                const int so = __builtin_amdgcn_readlane(vj, 17 + 2 * p);
                const int row = odd ? so : se;
                gv[8 + p] = Gp2[(size_t)row * 32 + m];
            }
        }

        // ---- GELU-accumulate ----
        float a00 = 0.f, a01 = 0.f, a10 = 0.f, a11 = 0.f;
        #pragma unroll
        for (int p = 0; p < 8; ++p) {
            const float2 xy = __half22float2(gv[p]);
            a00 += gelu_fast(xy.x - P00);
            a01 += gelu_fast(xy.y - P01);
        }
        if (has1) {
            #pragma unroll
            for (int p = 0; p < 8; ++p) {
                const float2 xy = __half22float2(gv[8 + p]);
                a10 += gelu_fast(xy.x - P10);
                a11 += gelu_fast(xy.y - P11);
            }
        }
        a00 *= (1.0f / KNN); a01 *= (1.0f / KNN);
        a10 *= (1.0f / KNN); a11 *= (1.0f / KNN);
        a00 += __shfl_xor(a00, 32, 64);
        a01 += __shfl_xor(a01, 32, 64);
        a10 += __shfl_xor(a10, 32, 64);
        a11 += __shfl_xor(a11, 32, 64);

        // ---- epilogue: out[i,c] += sum_d hbar[d] * W2[d,c] ----
        float o0 = out[(size_t)i0 * 64 + c];
        float o1 = has1 ? out[(size_t)i1 * 64 + c] : 0.f;
        #pragma unroll
        for (int d = 0; d < 64; ++d) {
            const float w = w2s[d * 64 + c];
            o0 = fmaf(lane_bcast((d & 1) ? a01 : a00, d >> 1), w, o0);
            o1 = fmaf(lane_bcast((d & 1) ? a11 : a10, d >> 1), w, o1);
        }
        out[(size_t)i0 * 64 + c] = o0;
        if (has1) out[(size_t)i1 * 64 + c] = o1;
    }
}

extern "C" void kernel_launch(void* const* d_in, const int* in_sizes, int n_in,
                              void* d_out, int out_size, void* d_ws, size_t ws_size,
                              hipStream_t stream) {
    const float* coords   = (const float*)d_in[0];
    const float* features = (const float*)d_in[1];
    const int*   idx      = (const int*)d_in[2];
    const float* W1       = (const float*)d_in[3];
    const float* b1       = (const float*)d_in[4];
    const float* W2       = (const float*)d_in[5];
    const float* b2       = (const float*)d_in[6];
    const float* Ws       = (const float*)d_in[7];
    const float* bs       = (const float*)d_in[8];
    float* out = (float*)d_out;
    const int n = in_sizes[0] / 3;            // 100000
    __half* Gp = (__half*)d_ws;               // n*64 halfs = 12.8 MB

    dim3 block(64, 4);
    gno_phase1<<<dim3(1024), block, 0, stream>>>(features, coords, W1, b1,
                                                 Ws, bs, b2, Gp, out, n);
    gno_phase2<<<dim3(1536), block, 0, stream>>>(coords, idx, W1, W2,
                                                 (const __half2*)Gp, out, n);
}